// Round 13
// baseline (199.584 us; speedup 1.0000x reference)
//
#include <hip/hip_runtime.h>

#define TOKENS 8192
#define IN_F   4096
#define OUT_F  4096

#define BM 256
#define BN 256
#define BKB 128              // K-bytes per tile (= 4 mfma K-steps of 32)
#define NT (IN_F / BKB)      // 32 K-tiles
#define NI (NT / 2)          // 16 outer iterations (2 tiles each)

using int4v  = __attribute__((ext_vector_type(4)))  int;
using int16v = __attribute__((ext_vector_type(16))) int;
typedef __attribute__((address_space(3))) char       lds_char_t;
typedef const __attribute__((address_space(1))) char glob_char_t;

// ---------------- pack int32 -> int8 (values already in [-128,127]) ----------------
__global__ void pack_i32_to_i8(const int* __restrict__ src, int* __restrict__ dst, int n4) {
    int stride = gridDim.x * blockDim.x;
    for (int i = blockIdx.x * blockDim.x + threadIdx.x; i < n4; i += stride) {
        int4v v = ((const int4v*)src)[i];
        dst[i] = (v.x & 0xff) | ((v.y & 0xff) << 8) | ((v.z & 0xff) << 16) | (v.w << 24);
    }
}

// ---------------- 256x256 i8 GEMM, 32x32x32 MFMA, E/O pipeline (race fixed) ----------------
// ROOT CAUSE of R9/R10/R12 failures: vmcnt is PER-WAVE and s_barrier does not
// wait for memory. Placing the staging drain AFTER a barrier lets wave w0 read
// LDS slices staged by wave w1 whose loads are still in flight. R4-R8 (passing)
// always drained BEFORE the barrier. FIX: VM0 at the END of P0/P2 (before BAR),
// draining each wave's stages so the post-barrier readers see landed data.
//   P0: stage B(u1)->s1 | read te.h1 | MFMA te.h0 | WK0 | VM0 | BAR
//   P1: stage A(u2)->s0 | read to.h0 | MFMA te.h1 | WK0 |       BAR
//   P2: stage B(u2)->s0 | read to.h1 | MFMA to.h0 | WK0 | VM0 | BAR
//   P3: stage A(u3)->s1 | read t(u2).h0 | MFMA to.h1 | WK0 |    BAR
// WK0 (lgkmcnt(0)) before every BAR => all this wave's ds_reads executed before
// any overwrite of that region can be issued (overwrites are >=1 barrier later).
// sched_barrier(0) fences around the MFMA cluster pin issue order (rule #18,
// both directions: reads stay before MFMA; MFMA stays before the drains).
// All waits are FULL drains (spill-immune). Layouts as R9-R12 (A/B k-map
// symmetric; C/D col=lane&31, row=(reg&3)+8*(reg>>2)+4*(lane>>5), guide-verified).
__global__ __launch_bounds__(512, 2) void qgemm_i8(
    const signed char* __restrict__ A,   // [M][K] int8
    const signed char* __restrict__ Bw,  // [N][K] int8
    const int*   __restrict__ bias,
    const float* __restrict__ wscale,
    const float* __restrict__ p_si, const float* __restrict__ p_so, const float* __restrict__ p_zp,
    int* __restrict__ C)
{
    constexpr int N = OUT_F, K = IN_F;
    constexpr int NBN = N / BN;  // 16

    __shared__ __align__(16) signed char smem[131072];

    // XCD-aware swizzle (nwg = 512, %8 == 0 -> bijective)
    int nwg = gridDim.x, bid = blockIdx.x, swz = bid;
    if ((nwg & 7) == 0) { int cpx = nwg >> 3; swz = (bid & 7) * cpx + (bid >> 3); }
    int bm = swz / NBN, bn = swz - bm * NBN;

    const int t = threadIdx.x, wid = t >> 6, l = t & 63;
    const int wr = wid >> 2, wc = wid & 3;
    const int l31 = l & 31, hi = l >> 5, l7 = l & 7;

    // frag-read bases (slot0): granule g = kk*2+hi, phys byte = row*128 + ((g^(row&7))<<4)
    const unsigned aB0 = (unsigned)(uintptr_t)((lds_char_t*)smem + (wr * 128 + l31) * 128);
    const unsigned bB0 = (unsigned)(uintptr_t)((lds_char_t*)smem + 32768 + (wc * 64 + l31) * 128);
    unsigned aB[4], bB[4];
    #pragma unroll
    for (int k = 0; k < 4; ++k) {
        unsigned x = (unsigned)(((k * 2 + hi) ^ l7) << 4);
        aB[k] = aB0 + x; bB[k] = bB0 + x;
    }

    // staging: thread t writes LDS-linear o = e*8192 + t*16 within a half-region
    // (row = e*64 + t>>3, granule = t&7); inverse-swizzled global column:
    const int srow = t >> 3;
    const int scol = (((t & 7) ^ ((t >> 3) & 7)) << 4);
    const signed char* gApl = A  + (size_t)(bm * BM + srow) * K + scol;
    const signed char* gBpl = Bw + (size_t)(bn * BN + srow) * K + scol;

#define STA(bufOff_, h_, tt_) do {                                                                 \
    __builtin_amdgcn_global_load_lds((glob_char_t*)(gApl + (size_t)((h_)*128      ) * K + (tt_)*BKB), \
        (lds_char_t*)smem + (bufOff_) + (h_)*16384 +        wid*1024, 16, 0, 0);                   \
    __builtin_amdgcn_global_load_lds((glob_char_t*)(gApl + (size_t)((h_)*128 + 64 ) * K + (tt_)*BKB), \
        (lds_char_t*)smem + (bufOff_) + (h_)*16384 + 8192 + wid*1024, 16, 0, 0);                   \
} while (0)
#define STB(bufOff_, h_, tt_) do {                                                                 \
    __builtin_amdgcn_global_load_lds((glob_char_t*)(gBpl + (size_t)((h_)*128      ) * K + (tt_)*BKB), \
        (lds_char_t*)smem + (bufOff_) + 32768 + (h_)*16384 +        wid*1024, 16, 0, 0);           \
    __builtin_amdgcn_global_load_lds((glob_char_t*)(gBpl + (size_t)((h_)*128 + 64 ) * K + (tt_)*BKB), \
        (lds_char_t*)smem + (bufOff_) + 32768 + (h_)*16384 + 8192 + wid*1024, 16, 0, 0);           \
} while (0)

#define DSR(dst_, base_, imm_) \
    asm volatile("ds_read_b128 %0, %1 offset:" #imm_ : "=&v"(dst_) : "v"(base_))

// 12 reads: one half-tile (kk pair k0_,k1_) of A (4 m-tiles) + B (2 n-tiles)
#define RDH(aF_, bF_, k0_, k1_) do {                                     \
    DSR(aF_[0][0], aB[k0_], 0);     DSR(aF_[0][1], aB[k1_], 0);          \
    DSR(aF_[1][0], aB[k0_], 4096);  DSR(aF_[1][1], aB[k1_], 4096);       \
    DSR(aF_[2][0], aB[k0_], 8192);  DSR(aF_[2][1], aB[k1_], 8192);       \
    DSR(aF_[3][0], aB[k0_], 12288); DSR(aF_[3][1], aB[k1_], 12288);      \
    DSR(bF_[0][0], bB[k0_], 0);     DSR(bF_[0][1], bB[k1_], 0);          \
    DSR(bF_[1][0], bB[k0_], 4096);  DSR(bF_[1][1], bB[k1_], 4096); } while (0)

#define SLOTP() do { _Pragma("unroll") for (int k_ = 0; k_ < 4; ++k_) { aB[k_] += 65536u; bB[k_] += 65536u; } } while (0)
#define SLOTM() do { _Pragma("unroll") for (int k_ = 0; k_ < 4; ++k_) { aB[k_] -= 65536u; bB[k_] -= 65536u; } } while (0)

#define MF(aF_, bF_) do { _Pragma("unroll") for (int kk = 0; kk < 2; ++kk)                         \
    _Pragma("unroll") for (int mi = 0; mi < 4; ++mi)                                               \
    _Pragma("unroll") for (int ni = 0; ni < 2; ++ni)                                               \
        acc[mi][ni] = __builtin_amdgcn_mfma_i32_32x32x32_i8(                                       \
            aF_[mi][kk], bF_[ni][kk], acc[mi][ni], 0, 0, 0); } while (0)

#define SCB __builtin_amdgcn_sched_barrier(0)
#define SP1 __builtin_amdgcn_s_setprio(1)
#define SP0 __builtin_amdgcn_s_setprio(0)
#define BAR __builtin_amdgcn_s_barrier()
#define VM0 asm volatile("s_waitcnt vmcnt(0)" ::: "memory")
#define WK0 do { asm volatile("s_waitcnt lgkmcnt(0)" ::: "memory"); SCB; } while (0)

    int16v acc[4][2] = {};
    int4v aE[4][2], aO[4][2], bE[2][2], bO[2][2];

    // ---- prologue: t0 A+B -> slot0, t1 A -> slot1; drain BEFORE barrier; read t0.h0
    STA(0, 0, 0); STA(0, 1, 0); STB(0, 0, 0); STB(0, 1, 0);
    STA(65536, 0, 1); STA(65536, 1, 1);
    VM0;                        // every wave's t0/t1A loads landed before anyone crosses
    BAR;
    RDH(aE, bE, 0, 1);          // t0.h0 frags (slot0, kk 0,1)
    WK0;

#define ITER_FULL(i_) do {                                                                         \
    const int u1 = 2*(i_) + 1, u2 = 2*(i_) + 2, u3 = 2*(i_) + 3;                                   \
    /*P0: stage B(u1)->s1; read te.h1; MFMA te.h0; drain reads+stages BEFORE BAR*/                 \
    STB(65536, 0, u1); STB(65536, 1, u1);                                                          \
    RDH(aO, bO, 2, 3); SCB; SP1; MF(aE, bE); SP0; SCB; WK0; VM0; SLOTP(); BAR;                     \
    /*P1: stage A(u2)->s0; read to.h0 (s1: A landed prev-P3+P0.VM0, B landed P0.VM0)*/             \
    STA(0, 0, u2); STA(0, 1, u2);                                                                  \
    RDH(aE, bE, 0, 1); SCB; SP1; MF(aO, bO); SP0; SCB; WK0; BAR;                                   \
    /*P2: stage B(u2)->s0; read to.h1; MFMA to.h0; drain (A(u2)+B(u2) landed) BEFORE BAR*/         \
    STB(0, 0, u2); STB(0, 1, u2);                                                                  \
    RDH(aO, bO, 2, 3); SCB; SP1; MF(aE, bE); SP0; SCB; WK0; VM0; SLOTM(); BAR;                     \
    /*P3: stage A(u3)->s1; read t(u2).h0 (s0, confirmed by P2.VM0); MFMA to.h1*/                   \
    STA(65536, 0, u3); STA(65536, 1, u3);                                                          \
    RDH(aE, bE, 0, 1); SCB; SP1; MF(aO, bO); SP0; SCB; WK0; BAR;                                   \
} while (0)

#define ITER_TAIL() do {                                                                           \
    /*T0: stage B(31)->s1; read t30.h1; MFMA t30.h0; drain before BAR*/                            \
    STB(65536, 0, 31); STB(65536, 1, 31);                                                          \
    RDH(aO, bO, 2, 3); SCB; SP1; MF(aE, bE); SP0; SCB; WK0; VM0; SLOTP(); BAR;                     \
    /*T1: read t31.h0 (s1: A staged prev-P3, B staged T0, both drained T0.VM0)*/                   \
    RDH(aE, bE, 0, 1); SCB; SP1; MF(aO, bO); SP0; SCB; WK0; BAR;                                   \
    /*T2: read t31.h1; MFMA t31.h0*/                                                               \
    RDH(aO, bO, 2, 3); SCB; SP1; MF(aE, bE); SP0; SCB; WK0;                                        \
    /*T3: MFMA t31.h1*/                                                                            \
    SP1; MF(aO, bO); SP0;                                                                          \
} while (0)

    for (int i = 0; i < NI - 1; ++i) ITER_FULL(i);
    ITER_TAIL();

#undef ITER_TAIL
#undef ITER_FULL
#undef WK0
#undef VM0
#undef BAR
#undef SP0
#undef SP1
#undef SCB
#undef MF
#undef SLOTM
#undef SLOTP
#undef RDH
#undef DSR
#undef STB
#undef STA

    // ---- epilogue: y = clip(rint(scale[n]*(acc+bias[n]) + zp)), stored as int32 ----
    float si = p_si[0], so = p_so[0], z = p_zp[0];
    float rs = si / so;

    #pragma unroll
    for (int ni = 0; ni < 2; ++ni) {
        int col = bn * BN + wc * 64 + ni * 32 + l31;
        float sc = wscale[col] * rs;
        int   bs = bias[col];
        #pragma unroll
        for (int mi = 0; mi < 4; ++mi) {
            int rowb = bm * BM + wr * 128 + mi * 32 + 4 * hi;
            #pragma unroll
            for (int r = 0; r < 16; ++r) {
                int row = rowb + (r & 3) + 8 * (r >> 2);
                float y = sc * (float)(acc[mi][ni][r] + bs) + z;
                y = rintf(y);
                y = fminf(fmaxf(y, -128.0f), 127.0f);
                C[(size_t)row * N + col] = (int)y;
            }
        }
    }
}

// ---------------- fallback if workspace too small: naive but exact ----------------
__global__ void qgemm_naive(const int* __restrict__ qx, const int* __restrict__ qw,
                            const int* __restrict__ bias, const float* __restrict__ wscale,
                            const float* __restrict__ si, const float* __restrict__ so,
                            const float* __restrict__ zp, int* __restrict__ out) {
    int idx = blockIdx.x * blockDim.x + threadIdx.x;
    if (idx >= TOKENS * OUT_F) return;
    int row = idx / OUT_F, col = idx - row * OUT_F;
    const int4v* xa = (const int4v*)(qx + (size_t)row * IN_F);
    const int4v* wb = (const int4v*)(qw + (size_t)col * IN_F);
    int acc = 0;
    for (int k = 0; k < IN_F / 4; ++k) {
        int4v a = xa[k], b = wb[k];
        acc += a.x * b.x + a.y * b.y + a.z * b.z + a.w * b.w;
    }
    float y = wscale[col] * si[0] / so[0] * (float)(acc + bias[col]) + zp[0];
    y = fminf(fmaxf(rintf(y), -128.0f), 127.0f);
    out[idx] = (int)y;
}

extern "C" void kernel_launch(void* const* d_in, const int* in_sizes, int n_in,
                              void* d_out, int out_size, void* d_ws, size_t ws_size,
                              hipStream_t stream) {
    const int*   q_x    = (const int*)d_in[0];
    const int*   q_w    = (const int*)d_in[1];
    const int*   bias   = (const int*)d_in[2];
    const float* wscale = (const float*)d_in[3];
    const float* s_in   = (const float*)d_in[4];
    const float* s_out  = (const float*)d_in[5];
    const float* zp     = (const float*)d_in[6];
    int* out = (int*)d_out;

    const size_t needA = (size_t)TOKENS * IN_F;  // 32 MiB
    const size_t needB = (size_t)OUT_F * IN_F;   // 16 MiB

    if (ws_size >= needA + needB) {
        signed char* pA = (signed char*)d_ws;
        signed char* pB = pA + needA;
        pack_i32_to_i8<<<2048, 256, 0, stream>>>(q_x, (int*)pA, (int)(needA / 4));
        pack_i32_to_i8<<<1024, 256, 0, stream>>>(q_w, (int*)pB, (int)(needB / 4));
        int grid = (TOKENS / BM) * (OUT_F / BN);  // 32*16 = 512
        qgemm_i8<<<grid, 512, 0, stream>>>(pA, pB, bias, wscale, s_in, s_out, zp, out);
    } else {
        int total = TOKENS * OUT_F;
        qgemm_naive<<<(total + 255) / 256, 256, 0, stream>>>(q_x, q_w, bias, wscale, s_in, s_out, zp, out);
    }
}

// Round 14
// 186.526 us; speedup vs baseline: 1.0700x; 1.0700x over previous
//
#include <hip/hip_runtime.h>

#define TOKENS 8192
#define IN_F   4096
#define OUT_F  4096

#define BM 256
#define BN 256
#define BKB 128              // K-bytes per tile (= 2 mfma K-steps of 64)
#define NT (IN_F / BKB)      // 32 K-tiles
#define NI (NT / 2)          // 16 outer iterations (2 tiles each)

using int4v = __attribute__((ext_vector_type(4))) int;
typedef __attribute__((address_space(3))) char       lds_char_t;
typedef const __attribute__((address_space(1))) char glob_char_t;

// ---------------- pack int32 -> int8 (values already in [-128,127]) ----------------
__global__ void pack_i32_to_i8(const int* __restrict__ src, int* __restrict__ dst, int n4) {
    int stride = gridDim.x * blockDim.x;
    for (int i = blockIdx.x * blockDim.x + threadIdx.x; i < n4; i += stride) {
        int4v v = ((const int4v*)src)[i];
        dst[i] = (v.x & 0xff) | ((v.y & 0xff) << 8) | ((v.z & 0xff) << 16) | (v.w << 24);
    }
}

// ---------------- 256x256 i8 GEMM: R8 kernel (verified, 134us) + chunked XCD map ----
// ONLY change vs R8: block->tile mapping. R8's linear swizzle gave each XCD a
// 2(bm) x 16(bn) panel set = 18 MB streamed per 32-block chunk; phase time was
// pinned at ~1250cy across 5 schedule variants => L2-fill/panel-stream bound
// (16KB/CU/phase staging = ~7.6 TB/s fill demand). New mapping: each XCD gets a
// 4(bm) x 8(bn) chunk (32 co-resident blocks) => 12 panel-MB per chunk (-33%
// fill traffic). Bijective for grid=512 (32x16 tiles, 8 XCDs, 2 rounds).
// Everything else byte-identical to R8 (verified schedule, WK/VM bookkeeping,
// swizzles, epilogue).
__global__ __launch_bounds__(512, 2) void qgemm_i8(
    const signed char* __restrict__ A,   // [M][K] int8
    const signed char* __restrict__ Bw,  // [N][K] int8
    const int*   __restrict__ bias,
    const float* __restrict__ wscale,
    const float* __restrict__ p_si, const float* __restrict__ p_so, const float* __restrict__ p_zp,
    int* __restrict__ C)
{
    constexpr int N = OUT_F, K = IN_F;
    constexpr int NBN = N / BN;  // 16

    __shared__ __align__(16) signed char smem[131072];

    // Chunked XCD-aware mapping (grid 512 = 32 bm x 16 bn; XCD = bid & 7):
    // chunk c = xcd + 8*round covers bm in [4*(c&7) .. +3], bn in [8*(c>>3) .. +7].
    int bid = blockIdx.x;
    int bm, bn;
    if (gridDim.x == 512) {
        int x = bid & 7;            // XCD (round-robin dispatch heuristic)
        int s = bid >> 3;           // 0..63 within XCD
        int r = s >> 5;             // round 0/1 (32 co-resident blocks/XCD)
        int u = s & 31;             // slot in chunk
        int c = x + 8 * r;          // chunk 0..15
        bm = (c & 7) * 4 + (u >> 3);
        bn = (c >> 3) * 8 + (u & 7);
    } else {
        int swz = bid;
        if ((gridDim.x & 7) == 0) { int cpx = gridDim.x >> 3; swz = (bid & 7) * cpx + (bid >> 3); }
        bm = swz / NBN; bn = swz - (swz / NBN) * NBN;
    }

    const int t = threadIdx.x, wid = t >> 6, l = t & 63;
    const int wr = wid >> 2, wc = wid & 3, lr = l & 15, lg = l >> 4;

    // ds_read offsets: frag (row, kk): byte = row*128 + ((kk*4+lg)^(lr&7))<<4
    const int k0off = ((lg       ^ (lr & 7)) << 4);
    const int k1off = (((4 + lg) ^ (lr & 7)) << 4);
    const int arow = (wr * 128 + lr) * 128;  // + m*2048
    const int brow = (wc * 64  + lr) * 128;  // + n*2048

    // staging: thread t writes LDS-linear o = e*8192 + t*16 within a half-tile
    // (row = e*64 + t>>3, col16 = t&7); inverse-swizzled global column:
    const int srow = t >> 3;                                  // 0..63
    const int scol = (((t & 7) ^ ((t >> 3) & 7)) << 4);
    const signed char* gApl = A  + (size_t)(bm * BM + srow) * K + scol;
    const signed char* gBpl = Bw + (size_t)(bn * BN + srow) * K + scol;

#define STA(bufOff_, h_, tt_) do {                                                                 \
    __builtin_amdgcn_global_load_lds((glob_char_t*)(gApl + (size_t)((h_)*128      ) * K + (tt_)*BKB), \
        (lds_char_t*)smem + (bufOff_) + (h_)*16384 +        wid*1024, 16, 0, 0);                   \
    __builtin_amdgcn_global_load_lds((glob_char_t*)(gApl + (size_t)((h_)*128 + 64 ) * K + (tt_)*BKB), \
        (lds_char_t*)smem + (bufOff_) + (h_)*16384 + 8192 + wid*1024, 16, 0, 0);                   \
} while (0)
#define STB(bufOff_, h_, tt_) do {                                                                 \
    __builtin_amdgcn_global_load_lds((glob_char_t*)(gBpl + (size_t)((h_)*128      ) * K + (tt_)*BKB), \
        (lds_char_t*)smem + (bufOff_) + 32768 + (h_)*16384 +        wid*1024, 16, 0, 0);           \
    __builtin_amdgcn_global_load_lds((glob_char_t*)(gBpl + (size_t)((h_)*128 + 64 ) * K + (tt_)*BKB), \
        (lds_char_t*)smem + (bufOff_) + 32768 + (h_)*16384 + 8192 + wid*1024, 16, 0, 0);           \
} while (0)

    // LDS byte-offset bases (32-bit AS(3) addresses) — swizzle folded in
#define LDSOFF(x_) ((unsigned)(uintptr_t)((lds_char_t*)smem + (x_)))
    const unsigned aB0k0 = LDSOFF(arow + k0off);
    const unsigned aB0k1 = LDSOFF(arow + k1off);
    const unsigned aB1k0 = aB0k0 + 65536u;
    const unsigned aB1k1 = aB0k1 + 65536u;
    const unsigned bB0k0 = LDSOFF(32768 + brow + k0off);
    const unsigned bB0k1 = LDSOFF(32768 + brow + k1off);
    const unsigned bB1k0 = bB0k0 + 65536u;
    const unsigned bB1k1 = bB0k1 + 65536u;

#define DSR(dst_, base_, imm_) \
    asm volatile("ds_read_b128 %0, %1 offset:" #imm_ : "=&v"(dst_) : "v"(base_))

#define RD_A_LO(p0_, p1_) do { \
    DSR(a[0][0], p0_, 0);     DSR(a[0][1], p1_, 0);     \
    DSR(a[1][0], p0_, 2048);  DSR(a[1][1], p1_, 2048);  \
    DSR(a[2][0], p0_, 4096);  DSR(a[2][1], p1_, 4096);  \
    DSR(a[3][0], p0_, 6144);  DSR(a[3][1], p1_, 6144);  } while (0)
#define RD_A_HI(p0_, p1_) do { \
    DSR(a[4][0], p0_, 8192);  DSR(a[4][1], p1_, 8192);  \
    DSR(a[5][0], p0_, 10240); DSR(a[5][1], p1_, 10240); \
    DSR(a[6][0], p0_, 12288); DSR(a[6][1], p1_, 12288); \
    DSR(a[7][0], p0_, 14336); DSR(a[7][1], p1_, 14336); } while (0)
#define RD_B_LO(p0_, p1_) do { \
    DSR(b[0][0], p0_, 0);     DSR(b[0][1], p1_, 0);     \
    DSR(b[1][0], p0_, 2048);  DSR(b[1][1], p1_, 2048);  } while (0)
#define RD_B_HI(p0_, p1_) do { \
    DSR(b[2][0], p0_, 4096);  DSR(b[2][1], p1_, 4096);  \
    DSR(b[3][0], p0_, 6144);  DSR(b[3][1], p1_, 6144);  } while (0)

#define MF(mb_, nb_) do { _Pragma("unroll") for (int kk = 0; kk < 2; ++kk)                         \
    _Pragma("unroll") for (int mm = 0; mm < 4; ++mm)                                               \
    _Pragma("unroll") for (int nn = 0; nn < 2; ++nn)                                               \
        acc[(mb_)+mm][(nb_)+nn] = __builtin_amdgcn_mfma_i32_16x16x64_i8(                           \
            a[(mb_)+mm][kk], b[(nb_)+nn][kk], acc[(mb_)+mm][(nb_)+nn], 0, 0, 0); } while (0)

#define SP1 __builtin_amdgcn_s_setprio(1)
#define SP0 __builtin_amdgcn_s_setprio(0)
#define BAR __builtin_amdgcn_s_barrier()
#define VM(n_) asm volatile("s_waitcnt vmcnt(" #n_ ")" ::: "memory")
// counted lgkm wait + fence so MFMAs cannot hoist above it (rule #18)
#define WK(n_) do { asm volatile("s_waitcnt lgkmcnt(" #n_ ")" ::: "memory"); \
                    __builtin_amdgcn_sched_barrier(0); } while (0)

    int4v acc[8][4] = {};
    int4v a[8][2], b[4][2];

    // ---- prologue: buf0 <- tile0 (A,B), buf1 <- tile1 (A only); confirm buf0; read tile0 frags
    STA(0, 0, 0); STA(0, 1, 0); STB(0, 0, 0); STB(0, 1, 0);
    STA(65536, 0, 1); STA(65536, 1, 1);
    VM(4);                      // first 8 loads (buf0 A+B) landed; buf1.A (4) may be in flight
    BAR;
    RD_B_LO(bB0k0, bB0k1); RD_A_LO(aB0k0, aB0k1);   // 12 reads feeding P1

#define ITER_FULL(i_) do {                                                                         \
    const int t1 = 2*(i_)+1, t2 = 2*(i_)+2, t3 = 2*(i_)+3;                                         \
    /*P1*/ STB(65536, 0, t1); RD_A_HI(aB0k0, aB0k1);                WK(8);  SP1; MF(0, 0); SP0;        BAR; \
    /*P2*/ STB(65536, 1, t1); RD_B_HI(bB0k0, bB0k1);                WK(4);  SP1; MF(4, 0); SP0;        BAR; \
    /*P3*/ STA(0, 0, t2);                                           WK(0);  SP1; MF(0, 2); SP0; VM(2); BAR; \
    /*P4*/ STA(0, 1, t2); RD_B_LO(bB1k0, bB1k1); RD_A_LO(aB1k0, aB1k1); WK(12); SP1; MF(4, 2); SP0;    BAR; \
    /*P5*/ STB(0, 0, t2); RD_A_HI(aB1k0, aB1k1);                    WK(8);  SP1; MF(0, 0); SP0;        BAR; \
    /*P6*/ STB(0, 1, t2); RD_B_HI(bB1k0, bB1k1);                    WK(4);  SP1; MF(4, 0); SP0;        BAR; \
    /*P7*/ STA(65536, 0, t3);                                       WK(0);  SP1; MF(0, 2); SP0; VM(2); BAR; \
    /*P8*/ STA(65536, 1, t3); RD_B_LO(bB0k0, bB0k1); RD_A_LO(aB0k0, aB0k1); WK(12); SP1; MF(4, 2); SP0; BAR; \
} while (0)

#define ITER_TAIL() do {                                                                           \
    /*P1*/ STB(65536, 0, 31); RD_A_HI(aB0k0, aB0k1);                WK(8);  SP1; MF(0, 0); SP0;        BAR; \
    /*P2*/ STB(65536, 1, 31); RD_B_HI(bB0k0, bB0k1);                WK(4);  SP1; MF(4, 0); SP0;        BAR; \
    /*P3*/                                                          WK(0);  SP1; MF(0, 2); SP0; VM(0); BAR; \
    /*P4*/ RD_B_LO(bB1k0, bB1k1); RD_A_LO(aB1k0, aB1k1);            WK(12); SP1; MF(4, 2); SP0;        BAR; \
    /*P5*/ RD_A_HI(aB1k0, aB1k1);                                   WK(8);  SP1; MF(0, 0); SP0;        BAR; \
    /*P6*/ RD_B_HI(bB1k0, bB1k1);                                   WK(4);  SP1; MF(4, 0); SP0;        BAR; \
    /*P7*/                                                          WK(0);  SP1; MF(0, 2); SP0;        BAR; \
    /*P8*/                                                          WK(0);  SP1; MF(4, 2); SP0;             \
} while (0)

    for (int i = 0; i < NI - 1; ++i) ITER_FULL(i);
    ITER_TAIL();

#undef ITER_TAIL
#undef ITER_FULL
#undef WK
#undef VM
#undef BAR
#undef SP0
#undef SP1
#undef MF
#undef RD_B_HI
#undef RD_B_LO
#undef RD_A_HI
#undef RD_A_LO
#undef DSR
#undef LDSOFF
#undef STB
#undef STA

    // ---- epilogue: y = clip(rint(scale[n]*(acc+bias[n]) + zp)), stored as int32 ----
    float si = p_si[0], so = p_so[0], z = p_zp[0];
    float rs = si / so;

    #pragma unroll
    for (int n = 0; n < 4; ++n) {
        int col = bn * BN + wc * 64 + n * 16 + lr;
        float sc = wscale[col] * rs;
        int   bs = bias[col];
        #pragma unroll
        for (int m = 0; m < 8; ++m) {
            int row = bm * BM + wr * 128 + m * 16 + lg * 4;
            #pragma unroll
            for (int r = 0; r < 4; ++r) {
                float y = sc * (float)(acc[m][n][r] + bs) + z;
                y = rintf(y);
                y = fminf(fmaxf(y, -128.0f), 127.0f);
                C[(size_t)(row + r) * N + col] = (int)y;
            }
        }
    }
}

// ---------------- fallback if workspace too small: naive but exact ----------------
__global__ void qgemm_naive(const int* __restrict__ qx, const int* __restrict__ qw,
                            const int* __restrict__ bias, const float* __restrict__ wscale,
                            const float* __restrict__ si, const float* __restrict__ so,
                            const float* __restrict__ zp, int* __restrict__ out) {
    int idx = blockIdx.x * blockDim.x + threadIdx.x;
    if (idx >= TOKENS * OUT_F) return;
    int row = idx / OUT_F, col = idx - row * OUT_F;
    const int4v* xa = (const int4v*)(qx + (size_t)row * IN_F);
    const int4v* wb = (const int4v*)(qw + (size_t)col * IN_F);
    int acc = 0;
    for (int k = 0; k < IN_F / 4; ++k) {
        int4v a = xa[k], b = wb[k];
        acc += a.x * b.x + a.y * b.y + a.z * b.z + a.w * b.w;
    }
    float y = wscale[col] * si[0] / so[0] * (float)(acc + bias[col]) + zp[0];
    y = fminf(fmaxf(rintf(y), -128.0f), 127.0f);
    out[idx] = (int)y;
}

extern "C" void kernel_launch(void* const* d_in, const int* in_sizes, int n_in,
                              void* d_out, int out_size, void* d_ws, size_t ws_size,
                              hipStream_t stream) {
    const int*   q_x    = (const int*)d_in[0];
    const int*   q_w    = (const int*)d_in[1];
    const int*   bias   = (const int*)d_in[2];
    const float* wscale = (const float*)d_in[3];
    const float* s_in   = (const float*)d_in[4];
    const float* s_out  = (const float*)d_in[5];
    const float* zp     = (const float*)d_in[6];
    int* out = (int*)d_out;

    const size_t needA = (size_t)TOKENS * IN_F;  // 32 MiB
    const size_t needB = (size_t)OUT_F * IN_F;   // 16 MiB

    if (ws_size >= needA + needB) {
        signed char* pA = (signed char*)d_ws;
        signed char* pB = pA + needA;
        pack_i32_to_i8<<<2048, 256, 0, stream>>>(q_x, (int*)pA, (int)(needA / 4));
        pack_i32_to_i8<<<1024, 256, 0, stream>>>(q_w, (int*)pB, (int)(needB / 4));
        int grid = (TOKENS / BM) * (OUT_F / BN);  // 32*16 = 512
        qgemm_i8<<<grid, 512, 0, stream>>>(pA, pB, bias, wscale, s_in, s_out, zp, out);
    } else {
        int total = TOKENS * OUT_F;
        qgemm_naive<<<(total + 255) / 256, 256, 0, stream>>>(q_x, q_w, bias, wscale, s_in, s_out, zp, out);
    }
}